// Round 9
// baseline (106.708 us; speedup 1.0000x reference)
//
#include <hip/hip_runtime.h>
#include <hip/hip_bf16.h>

#define NN 100000
#define EE 1600000
#define ET (EE + NN)            // edges incl. self loops
#define HID 64
#define NEG 0.2f
#define NBUK 782                // ceil(NN/128) buckets of 128 dst nodes
#define SCT_TILE 4096           // edges per block in scatter phase
#define BUKCAP 4096             // padded per-bucket capacity (mean 2176, sigma~47)
#define SH_CAP 4096

// ---------------- kernel 0: xp = pad(x) [N][8] f32; ss1/sd1 node scores; zero bcur ----------------
__global__ __launch_bounds__(256) void k_proj(const float* __restrict__ x,
                                              const float* __restrict__ W1,
                                              const float* __restrict__ a_src1,
                                              const float* __restrict__ a_dst1,
                                              float* __restrict__ xp,
                                              float* __restrict__ ss1,
                                              float* __restrict__ sd1,
                                              int* __restrict__ bcur) {
    if (blockIdx.x == 0) {
        for (int i = threadIdx.x; i < 1024; i += 256) bcur[i] = 0;
    }
    int wid  = threadIdx.x >> 6;
    int lane = threadIdx.x & 63;
    int n = blockIdx.x * 4 + wid;
    if (n >= NN) return;
    float h = 0.f;
#pragma unroll
    for (int k = 0; k < 5; ++k) h += x[n * 5 + k] * W1[k * HID + lane];
    float a = h * a_src1[lane];
    float b = h * a_dst1[lane];
#pragma unroll
    for (int o = 32; o; o >>= 1) { a += __shfl_xor(a, o); b += __shfl_xor(b, o); }
    if (lane == 0) { ss1[n] = a; sd1[n] = b; }
    if (lane < 8) xp[(size_t)n * 8 + lane] = (lane < 5) ? x[n * 5 + lane] : 0.f;
}

// ---------------- CSR scatter: bucket-sort each tile in LDS, flush contiguously ----------------
__global__ __launch_bounds__(256) void k_bscatter(const int* __restrict__ ei,
                                                  int* __restrict__ bcur,
                                                  unsigned* __restrict__ pairs) {
    __shared__ unsigned sp[SCT_TILE];
    __shared__ unsigned ga[SCT_TILE];
    __shared__ int h[NBUK], loc[NBUK], cur[NBUK];
    __shared__ int wsum[4];
    int tid = threadIdx.x;
    int wid = tid >> 6, lane = tid & 63;
    int base = blockIdx.x * SCT_TILE;
    int tilecnt = ET - base; if (tilecnt > SCT_TILE) tilecnt = SCT_TILE;

    for (int i = tid; i < NBUK; i += 256) h[i] = 0;
    __syncthreads();
    int sreg[SCT_TILE / 256], dreg[SCT_TILE / 256];
#pragma unroll
    for (int it = 0; it < SCT_TILE / 256; ++it) {
        int i = base + it * 256 + tid;
        if (i < ET) {
            int s, d;
            if (i < EE) { s = ei[i]; d = ei[EE + i]; }
            else        { s = i - EE; d = s; }
            sreg[it] = s; dreg[it] = d;
            atomicAdd(&h[d >> 7], 1);
        } else dreg[it] = -1;
    }
    __syncthreads();
    int b0 = tid * 4;
    int s0 = 0;
    if (b0 < NBUK)
        for (int k = 0; k < 4 && b0 + k < NBUK; ++k) s0 += h[b0 + k];
    int incl = s0;
#pragma unroll
    for (int o = 1; o < 64; o <<= 1) {
        int t = __shfl(incl, (lane - o) & 63);
        if (lane >= o) incl += t;
    }
    if (lane == 63) wsum[wid] = incl;
    __syncthreads();
    int wpref = 0;
    for (int w = 0; w < wid; ++w) wpref += wsum[w];
    if (b0 < NBUK) {
        int run = wpref + incl - s0;
        for (int k = 0; k < 4 && b0 + k < NBUK; ++k) {
            loc[b0 + k] = run;
            run += h[b0 + k];
        }
    }
    __syncthreads();
    for (int i = tid; i < NBUK; i += 256) {
        int c = h[i];
        cur[i] = c ? (atomicAdd(&bcur[i], c) + i * BUKCAP - loc[i]) : 0;
    }
    __syncthreads();
#pragma unroll
    for (int it = 0; it < SCT_TILE / 256; ++it) {
        if (dreg[it] >= 0) {
            int s = sreg[it], d = dreg[it];
            int b = d >> 7;
            unsigned pk = ((unsigned)(d & 127) << 17) | (unsigned)s;
            int pos = atomicAdd(&loc[b], 1);
            sp[pos] = pk;
            ga[pos] = (unsigned)(cur[b] + pos);
        }
    }
    __syncthreads();
    for (int i = tid; i < tilecnt; i += 256)
        pairs[ga[i]] = sp[i];
}

// ---------------- fused: per-bucket counting sort (LDS) + layer-1 softmax-aggregate ----------------
// generic (deg>32) node path: full wave, srcs from LDS
__device__ __forceinline__ void agg1_gen_lds(int n, int off, int deg, int lane,
                                             const int* srt,
                                             const float* __restrict__ ss1,
                                             const float* __restrict__ sd1,
                                             const float* __restrict__ xp,
                                             const float* __restrict__ W1,
                                             const float* __restrict__ b1,
                                             const float* __restrict__ W2,
                                             float* __restrict__ h2) {
    float sdn = sd1[n];
    float m = -1e30f;
    for (int j0 = 0; j0 < deg; j0 += 64) {
        int j = j0 + lane;
        if (j < deg) {
            int s = srt[off + j];
            float e = ss1[s] + sdn;
            e = e > 0.f ? e : NEG * e;
            m = fmaxf(m, e);
        }
    }
#pragma unroll
    for (int o = 32; o; o >>= 1) m = fmaxf(m, __shfl_xor(m, o));
    float dsum = 0.f;
    for (int j0 = 0; j0 < deg; j0 += 64) {
        int j = j0 + lane;
        if (j < deg) {
            int s = srt[off + j];
            float e = ss1[s] + sdn;
            e = e > 0.f ? e : NEG * e;
            dsum += __expf(e - m);
        }
    }
#pragma unroll
    for (int o = 32; o; o >>= 1) dsum += __shfl_xor(dsum, o);
    float inv = 1.0f / dsum;
    float a0 = 0.f, a1 = 0.f, a2 = 0.f, a3 = 0.f, a4 = 0.f;
    for (int j0 = 0; j0 < deg; j0 += 64) {
        int j = j0 + lane;
        if (j < deg) {
            int s = srt[off + j];
            float e = ss1[s] + sdn;
            e = e > 0.f ? e : NEG * e;
            float w = __expf(e - m) * inv;
            const float4 xa = *(const float4*)(xp + (size_t)s * 8);
            float x4 = xp[(size_t)s * 8 + 4];
            a0 += w * xa.x; a1 += w * xa.y; a2 += w * xa.z; a3 += w * xa.w; a4 += w * x4;
        }
    }
#pragma unroll
    for (int o = 32; o; o >>= 1) {
        a0 += __shfl_xor(a0, o); a1 += __shfl_xor(a1, o); a2 += __shfl_xor(a2, o);
        a3 += __shfl_xor(a3, o); a4 += __shfl_xor(a4, o);
    }
    float of = b1[lane] + a0 * W1[lane] + a1 * W1[64 + lane] + a2 * W1[128 + lane]
             + a3 * W1[192 + lane] + a4 * W1[256 + lane];
    of = fmaxf(of, 0.f);
    float p2 = of * W2[lane];
#pragma unroll
    for (int o = 32; o; o >>= 1) p2 += __shfl_xor(p2, o);
    if (lane == 0) h2[n] = p2;
}

__global__ __launch_bounds__(512) void k_fused(const int* __restrict__ bcur,
                                               unsigned* __restrict__ pairs,
                                               int* __restrict__ rowptr,
                                               int* __restrict__ cntd,
                                               const float* __restrict__ ss1,
                                               const float* __restrict__ sd1,
                                               const float* __restrict__ xp,
                                               const float* __restrict__ W1,
                                               const float* __restrict__ b1,
                                               const float* __restrict__ W2,
                                               float* __restrict__ h2) {
    __shared__ unsigned sp[SH_CAP];
    __shared__ int srt[SH_CAP];
    __shared__ int hist[128], sc[128], cur2[128];
    int b = blockIdx.x;
    int cnt = bcur[b];
    if (cnt > SH_CAP) cnt = SH_CAP;   // statistically impossible; memory-safety only
    int base = b * BUKCAP;
    int tid = threadIdx.x;
    if (tid < 128) hist[tid] = 0;
    __syncthreads();
    for (int i = tid; i < cnt; i += 512) {
        unsigned p = pairs[base + i];
        sp[i] = p;
        atomicAdd(&hist[p >> 17], 1);
    }
    __syncthreads();
    // 128-bin exclusive scan on wave 0
    if (tid < 64) {
        int v0 = hist[2 * tid], v1 = hist[2 * tid + 1];
        int s = v0 + v1;
#pragma unroll
        for (int o = 1; o < 64; o <<= 1) {
            int t = __shfl(s, (tid - o) & 63);
            if (tid >= o) s += t;
        }
        int excl = s - v0 - v1;
        sc[2 * tid] = excl;
        sc[2 * tid + 1] = excl + v0;
    }
    __syncthreads();
    int nbase = b << 7;
    if (tid < 128) {
        cur2[tid] = sc[tid];
        if (nbase + tid < NN) {
            rowptr[nbase + tid] = base + sc[tid];
            cntd[nbase + tid]   = hist[tid];
        }
    }
    __syncthreads();
    // counting-sort scatter: srt (LDS, for this kernel) + adj (global, for k_agg2)
    int* adj = (int*)pairs;   // aliases pairs; all pairs reads completed above
    for (int i = tid; i < cnt; i += 512) {
        unsigned p = sp[i];
        int ld = p >> 17;
        int pos = atomicAdd(&cur2[ld], 1);
        int s = (int)(p & 0x1FFFF);
        srt[pos] = s;
        adj[base + pos] = s;
    }
    __syncthreads();

    // ---- aggregation: 8 waves x 8 sequential node-pairs ----
    int wid  = tid >> 6;
    int lane = tid & 63;
    for (int pp = wid; pp < 64; pp += 8) {
        int l0 = pp * 2, l1 = pp * 2 + 1;
        int n0g = nbase + l0;
        if (n0g >= NN) break;
        bool has1 = (nbase + l1) < NN;
        int d0 = hist[l0];
        int d1 = has1 ? hist[l1] : 0;
        if (d0 <= 32 && d1 <= 32) {
            int half = lane >> 5, li = lane & 31;
            int ln = half ? l1 : l0;
            int n = nbase + ln;
            bool valid = half ? has1 : true;
            int deg = half ? d1 : d0;
            int off = sc[ln];
            float sdn = valid ? sd1[n] : 0.f;
            int s = srt[off + (li < deg ? li : 0)] & 0x1FFFF;
            const float4 xa = *(const float4*)(xp + (size_t)s * 8);
            float x4 = xp[(size_t)s * 8 + 4];
            float t = ss1[s] + sdn;
            float e = t > 0.f ? t : NEG * t;
            if (li >= deg) e = -1e30f;
            float m = e;
#pragma unroll
            for (int o = 1; o <= 16; o <<= 1) m = fmaxf(m, __shfl_xor(m, o));
            float p = (li < deg) ? __expf(e - m) : 0.f;
            float ds = p;
#pragma unroll
            for (int o = 1; o <= 16; o <<= 1) ds += __shfl_xor(ds, o);
            float w = p * (1.0f / ds);
            float a0 = w * xa.x, a1 = w * xa.y, a2 = w * xa.z, a3 = w * xa.w, a4 = w * x4;
#pragma unroll
            for (int o = 1; o <= 16; o <<= 1) {
                a0 += __shfl_xor(a0, o); a1 += __shfl_xor(a1, o); a2 += __shfl_xor(a2, o);
                a3 += __shfl_xor(a3, o); a4 += __shfl_xor(a4, o);
            }
            float o0 = b1[li] + a0 * W1[li] + a1 * W1[64 + li] + a2 * W1[128 + li]
                     + a3 * W1[192 + li] + a4 * W1[256 + li];
            float o1 = b1[li + 32] + a0 * W1[li + 32] + a1 * W1[96 + li] + a2 * W1[160 + li]
                     + a3 * W1[224 + li] + a4 * W1[288 + li];
            o0 = fmaxf(o0, 0.f);
            o1 = fmaxf(o1, 0.f);
            float p2 = o0 * W2[li] + o1 * W2[li + 32];
#pragma unroll
            for (int o = 1; o <= 16; o <<= 1) p2 += __shfl_xor(p2, o);
            if (li == 0 && valid) h2[n] = p2;
        } else {
            agg1_gen_lds(n0g, sc[l0], d0, lane, srt, ss1, sd1, xp, W1, b1, W2, h2);
            if (has1)
                agg1_gen_lds(nbase + l1, sc[l1], d1, lane, srt, ss1, sd1, xp, W1, b1, W2, h2);
        }
    }
}

// ---------------- layer 2: full-wave single-node fallback ----------------
__device__ __forceinline__ void agg2_node(int n, int lane,
                                          const int* __restrict__ rowptr,
                                          const int* __restrict__ cntd,
                                          const int* __restrict__ adj,
                                          const float* __restrict__ h2,
                                          float as2v, float ad2v, float b2v,
                                          float* __restrict__ out) {
    int off = rowptr[n], deg = cntd[n];
    float sdn = h2[n] * ad2v;
    float m = -1e30f;
    for (int j0 = 0; j0 < deg; j0 += 64) {
        int j = j0 + lane;
        if (j < deg) {
            int s = adj[off + j];
            float e = h2[s] * as2v + sdn;
            e = e > 0.f ? e : NEG * e;
            m = fmaxf(m, e);
        }
    }
#pragma unroll
    for (int o = 32; o; o >>= 1) m = fmaxf(m, __shfl_xor(m, o));
    float dsum = 0.f, nsum = 0.f;
    for (int j0 = 0; j0 < deg; j0 += 64) {
        int j = j0 + lane;
        if (j < deg) {
            int s = adj[off + j];
            float hv = h2[s];
            float e = hv * as2v + sdn;
            e = e > 0.f ? e : NEG * e;
            float ex = __expf(e - m);
            dsum += ex;
            nsum += ex * hv;
        }
    }
#pragma unroll
    for (int o = 32; o; o >>= 1) { dsum += __shfl_xor(dsum, o); nsum += __shfl_xor(nsum, o); }
    if (lane == 0) out[n] = nsum / dsum + b2v;
}

// ---------------- layer 2: 4 nodes per wave ----------------
__global__ __launch_bounds__(256) void k_agg2(const int* __restrict__ rowptr,
                                              const int* __restrict__ cntd,
                                              const int* __restrict__ adj,
                                              const float* __restrict__ h2,
                                              const float* __restrict__ as2,
                                              const float* __restrict__ ad2,
                                              const float* __restrict__ b2,
                                              float* __restrict__ out) {
    int wid  = threadIdx.x >> 6;
    int lane = threadIdx.x & 63;
    int n0 = (blockIdx.x * 4 + wid) * 4;
    if (n0 >= NN) return;
    float as2v = as2[0], ad2v = ad2[0], b2v = b2[0];
    int d0 = cntd[n0], d1 = cntd[n0 + 1], d2 = cntd[n0 + 2], d3 = cntd[n0 + 3];

    if (d0 <= 32 && d1 <= 32 && d2 <= 32 && d3 <= 32) {
        int half = lane >> 5, li = lane & 31;
        int nA = n0 + half, nB = n0 + 2 + half;
        int offA = rowptr[nA], offB = rowptr[nB];
        int degA = half ? d1 : d0, degB = half ? d3 : d2;
        float sdA = h2[nA] * ad2v, sdB = h2[nB] * ad2v;
        float hvA = 0.f, hvB = 0.f, eA = -1e30f, eB = -1e30f;
        if (li < degA) {
            hvA = h2[adj[offA + li]];
            float t = hvA * as2v + sdA;
            eA = t > 0.f ? t : NEG * t;
        }
        if (li < degB) {
            hvB = h2[adj[offB + li]];
            float t = hvB * as2v + sdB;
            eB = t > 0.f ? t : NEG * t;
        }
        float mA = eA, mB = eB;
#pragma unroll
        for (int o = 1; o <= 16; o <<= 1) {
            mA = fmaxf(mA, __shfl_xor(mA, o));
            mB = fmaxf(mB, __shfl_xor(mB, o));
        }
        float pA = (li < degA) ? __expf(eA - mA) : 0.f;
        float pB = (li < degB) ? __expf(eB - mB) : 0.f;
        float dsA = pA, dsB = pB, nsA = pA * hvA, nsB = pB * hvB;
#pragma unroll
        for (int o = 1; o <= 16; o <<= 1) {
            dsA += __shfl_xor(dsA, o); nsA += __shfl_xor(nsA, o);
            dsB += __shfl_xor(dsB, o); nsB += __shfl_xor(nsB, o);
        }
        if (li == 0) {
            out[nA] = nsA / dsA + b2v;
            out[nB] = nsB / dsB + b2v;
        }
    } else {
        agg2_node(n0,     lane, rowptr, cntd, adj, h2, as2v, ad2v, b2v, out);
        agg2_node(n0 + 1, lane, rowptr, cntd, adj, h2, as2v, ad2v, b2v, out);
        agg2_node(n0 + 2, lane, rowptr, cntd, adj, h2, as2v, ad2v, b2v, out);
        agg2_node(n0 + 3, lane, rowptr, cntd, adj, h2, as2v, ad2v, b2v, out);
    }
}

extern "C" void kernel_launch(void* const* d_in, const int* in_sizes, int n_in,
                              void* d_out, int out_size, void* d_ws, size_t ws_size,
                              hipStream_t stream) {
    const float* x      = (const float*)d_in[0];
    const int*   ei     = (const int*)d_in[1];
    const float* W1     = (const float*)d_in[2];
    const float* a_src1 = (const float*)d_in[3];
    const float* a_dst1 = (const float*)d_in[4];
    const float* b1     = (const float*)d_in[5];
    const float* W2     = (const float*)d_in[6];
    const float* as2    = (const float*)d_in[7];
    const float* ad2    = (const float*)d_in[8];
    const float* b2     = (const float*)d_in[9];
    float* out = (float*)d_out;

    // workspace layout (all 4-byte elements)
    float* xp   = (float*)d_ws;                         // N*8 f32 = 3.2MB
    float* ss1  = xp + (size_t)NN * 8;                  // N
    float* sd1  = ss1 + NN;                             // N
    float* h2   = sd1 + NN;                             // N
    int* rowptr = (int*)(h2 + NN);                      // N
    int* cntd   = rowptr + NN;                          // N
    int* bcur   = cntd + NN;                            // 1024
    unsigned* pairs = (unsigned*)(bcur + 1024);         // NBUK*BUKCAP (reused as adj)
    int* adj    = (int*)pairs;

    const int NSCT = (ET + SCT_TILE - 1) / SCT_TILE;    // 416
    const int NQUAD = (NN + 15) / 16;                   // 6250 blocks, 4 nodes/wave

    k_proj<<<(NN + 3) / 4, 256, 0, stream>>>(x, W1, a_src1, a_dst1, xp, ss1, sd1, bcur);
    k_bscatter<<<NSCT, 256, 0, stream>>>(ei, bcur, pairs);
    k_fused<<<NBUK, 512, 0, stream>>>(bcur, pairs, rowptr, cntd, ss1, sd1, xp, W1, b1, W2, h2);
    k_agg2<<<NQUAD, 256, 0, stream>>>(rowptr, cntd, adj, h2, as2, ad2, b2, out);
}

// Round 10
// 106.585 us; speedup vs baseline: 1.0012x; 1.0012x over previous
//
#include <hip/hip_runtime.h>
#include <hip/hip_bf16.h>

#define NN 100000
#define EE 1600000
#define ET (EE + NN)            // edges incl. self loops
#define HID 64
#define NEG 0.2f
#define NBUK 782                // ceil(NN/128) buckets of 128 dst nodes
#define SCT_TILE 4096           // edges per block in scatter phase
#define BUKCAP 4096             // padded per-bucket capacity (mean 2176, sigma~47)
#define HALFCAP 2048            // per-half-bucket capacity (mean 1088)

// ---------------- kernel 0: xp = pad(x) [N][8] f32; ss1/sd1 node scores; zero bcur ----------------
__global__ __launch_bounds__(256) void k_proj(const float* __restrict__ x,
                                              const float* __restrict__ W1,
                                              const float* __restrict__ a_src1,
                                              const float* __restrict__ a_dst1,
                                              float* __restrict__ xp,
                                              float* __restrict__ ss1,
                                              float* __restrict__ sd1,
                                              int* __restrict__ bcur) {
    if (blockIdx.x == 0) {
        for (int i = threadIdx.x; i < 1024; i += 256) bcur[i] = 0;
    }
    int wid  = threadIdx.x >> 6;
    int lane = threadIdx.x & 63;
    int n = blockIdx.x * 4 + wid;
    if (n >= NN) return;
    float h = 0.f;
#pragma unroll
    for (int k = 0; k < 5; ++k) h += x[n * 5 + k] * W1[k * HID + lane];
    float a = h * a_src1[lane];
    float b = h * a_dst1[lane];
#pragma unroll
    for (int o = 32; o; o >>= 1) { a += __shfl_xor(a, o); b += __shfl_xor(b, o); }
    if (lane == 0) { ss1[n] = a; sd1[n] = b; }
    if (lane < 8) xp[(size_t)n * 8 + lane] = (lane < 5) ? x[n * 5 + lane] : 0.f;
}

// ---------------- CSR scatter: bucket-sort each tile in LDS, flush contiguously ----------------
__global__ __launch_bounds__(256) void k_bscatter(const int* __restrict__ ei,
                                                  int* __restrict__ bcur,
                                                  unsigned* __restrict__ pairs) {
    __shared__ unsigned sp[SCT_TILE];
    __shared__ unsigned ga[SCT_TILE];
    __shared__ int h[NBUK], loc[NBUK], cur[NBUK];
    __shared__ int wsum[4];
    int tid = threadIdx.x;
    int wid = tid >> 6, lane = tid & 63;
    int base = blockIdx.x * SCT_TILE;
    int tilecnt = ET - base; if (tilecnt > SCT_TILE) tilecnt = SCT_TILE;

    for (int i = tid; i < NBUK; i += 256) h[i] = 0;
    __syncthreads();
    int sreg[SCT_TILE / 256], dreg[SCT_TILE / 256];
#pragma unroll
    for (int it = 0; it < SCT_TILE / 256; ++it) {
        int i = base + it * 256 + tid;
        if (i < ET) {
            int s, d;
            if (i < EE) { s = ei[i]; d = ei[EE + i]; }
            else        { s = i - EE; d = s; }
            sreg[it] = s; dreg[it] = d;
            atomicAdd(&h[d >> 7], 1);
        } else dreg[it] = -1;
    }
    __syncthreads();
    int b0 = tid * 4;
    int s0 = 0;
    if (b0 < NBUK)
        for (int k = 0; k < 4 && b0 + k < NBUK; ++k) s0 += h[b0 + k];
    int incl = s0;
#pragma unroll
    for (int o = 1; o < 64; o <<= 1) {
        int t = __shfl(incl, (lane - o) & 63);
        if (lane >= o) incl += t;
    }
    if (lane == 63) wsum[wid] = incl;
    __syncthreads();
    int wpref = 0;
    for (int w = 0; w < wid; ++w) wpref += wsum[w];
    if (b0 < NBUK) {
        int run = wpref + incl - s0;
        for (int k = 0; k < 4 && b0 + k < NBUK; ++k) {
            loc[b0 + k] = run;
            run += h[b0 + k];
        }
    }
    __syncthreads();
    for (int i = tid; i < NBUK; i += 256) {
        int c = h[i];
        cur[i] = c ? (atomicAdd(&bcur[i], c) + i * BUKCAP - loc[i]) : 0;
    }
    __syncthreads();
#pragma unroll
    for (int it = 0; it < SCT_TILE / 256; ++it) {
        if (dreg[it] >= 0) {
            int s = sreg[it], d = dreg[it];
            int b = d >> 7;
            unsigned pk = ((unsigned)(d & 127) << 17) | (unsigned)s;
            int pos = atomicAdd(&loc[b], 1);
            sp[pos] = pk;
            ga[pos] = (unsigned)(cur[b] + pos);
        }
    }
    __syncthreads();
    for (int i = tid; i < tilecnt; i += 256)
        pairs[ga[i]] = sp[i];
}

// ---------------- fused: half-bucket counting sort (LDS) + layer-1 softmax-aggregate ----------------
// generic (deg>32) node path: full wave, srcs from LDS
__device__ __forceinline__ void agg1_gen_lds(int n, int off, int deg, int lane,
                                             const int* srt,
                                             const float* __restrict__ ss1,
                                             const float* __restrict__ sd1,
                                             const float* __restrict__ xp,
                                             const float* __restrict__ W1,
                                             const float* __restrict__ b1,
                                             const float* __restrict__ W2,
                                             float* __restrict__ h2) {
    float sdn = sd1[n];
    float m = -1e30f;
    for (int j0 = 0; j0 < deg; j0 += 64) {
        int j = j0 + lane;
        if (j < deg) {
            int s = srt[off + j];
            float e = ss1[s] + sdn;
            e = e > 0.f ? e : NEG * e;
            m = fmaxf(m, e);
        }
    }
#pragma unroll
    for (int o = 32; o; o >>= 1) m = fmaxf(m, __shfl_xor(m, o));
    float dsum = 0.f;
    for (int j0 = 0; j0 < deg; j0 += 64) {
        int j = j0 + lane;
        if (j < deg) {
            int s = srt[off + j];
            float e = ss1[s] + sdn;
            e = e > 0.f ? e : NEG * e;
            dsum += __expf(e - m);
        }
    }
#pragma unroll
    for (int o = 32; o; o >>= 1) dsum += __shfl_xor(dsum, o);
    float inv = 1.0f / dsum;
    float a0 = 0.f, a1 = 0.f, a2 = 0.f, a3 = 0.f, a4 = 0.f;
    for (int j0 = 0; j0 < deg; j0 += 64) {
        int j = j0 + lane;
        if (j < deg) {
            int s = srt[off + j];
            float e = ss1[s] + sdn;
            e = e > 0.f ? e : NEG * e;
            float w = __expf(e - m) * inv;
            const float4 xa = *(const float4*)(xp + (size_t)s * 8);
            float x4 = xp[(size_t)s * 8 + 4];
            a0 += w * xa.x; a1 += w * xa.y; a2 += w * xa.z; a3 += w * xa.w; a4 += w * x4;
        }
    }
#pragma unroll
    for (int o = 32; o; o >>= 1) {
        a0 += __shfl_xor(a0, o); a1 += __shfl_xor(a1, o); a2 += __shfl_xor(a2, o);
        a3 += __shfl_xor(a3, o); a4 += __shfl_xor(a4, o);
    }
    float of = b1[lane] + a0 * W1[lane] + a1 * W1[64 + lane] + a2 * W1[128 + lane]
             + a3 * W1[192 + lane] + a4 * W1[256 + lane];
    of = fmaxf(of, 0.f);
    float p2 = of * W2[lane];
#pragma unroll
    for (int o = 32; o; o >>= 1) p2 += __shfl_xor(p2, o);
    if (lane == 0) h2[n] = p2;
}

// one block per 64-node half-bucket; pairs read twice from L2 (edge order is irrelevant)
__global__ __launch_bounds__(256) void k_fused(const int* __restrict__ bcur,
                                               const unsigned* __restrict__ pairs,
                                               int* __restrict__ adj,
                                               int* __restrict__ rowptr,
                                               int* __restrict__ cntd,
                                               const float* __restrict__ ss1,
                                               const float* __restrict__ sd1,
                                               const float* __restrict__ xp,
                                               const float* __restrict__ W1,
                                               const float* __restrict__ b1,
                                               const float* __restrict__ W2,
                                               float* __restrict__ h2) {
    __shared__ int srt[HALFCAP];
    __shared__ int hist[64], sc[64], cur2[64];
    int blk = blockIdx.x;
    int b = blk >> 1, half = blk & 1;
    int cnt = bcur[b];
    if (cnt > BUKCAP) cnt = BUKCAP;
    int base = b * BUKCAP;
    int tid = threadIdx.x;
    if (tid < 64) hist[tid] = 0;
    __syncthreads();
    // pass 1: histogram of this half's 64 nodes
    for (int i = tid; i < cnt; i += 256) {
        unsigned p = pairs[base + i];
        int ld = (int)(p >> 17);
        if ((ld >> 6) == half) atomicAdd(&hist[ld & 63], 1);
    }
    __syncthreads();
    // 64-bin exclusive scan on wave 0 (lane = bin)
    if (tid < 64) {
        int v = hist[tid];
        int s = v;
#pragma unroll
        for (int o = 1; o < 64; o <<= 1) {
            int t = __shfl(s, (tid - o) & 63);
            if (tid >= o) s += t;
        }
        sc[tid] = s - v;
        cur2[tid] = s - v;
    }
    __syncthreads();
    int nbase = (b << 7) + (half << 6);
    int gbase = base + half * HALFCAP;
    if (tid < 64 && nbase + tid < NN) {
        rowptr[nbase + tid] = gbase + sc[tid];
        cntd[nbase + tid]   = hist[tid];
    }
    __syncthreads();
    // pass 2: counting-sort scatter -> srt (LDS) + adj (global, for k_agg2)
    for (int i = tid; i < cnt; i += 256) {
        unsigned p = pairs[base + i];
        int ld = (int)(p >> 17);
        if ((ld >> 6) == half) {
            int pos = atomicAdd(&cur2[ld & 63], 1);
            if (pos < HALFCAP) {
                int s = (int)(p & 0x1FFFF);
                srt[pos] = s;
                adj[gbase + pos] = s;
            }
        }
    }
    __syncthreads();

    // ---- aggregation: 4 waves x 8 sequential node-pairs over 64 nodes ----
    int wid  = tid >> 6;
    int lane = tid & 63;
    for (int pp = wid; pp < 32; pp += 4) {
        int l0 = pp * 2, l1 = pp * 2 + 1;
        int n0g = nbase + l0;
        if (n0g >= NN) break;
        bool has1 = (nbase + l1) < NN;
        int d0 = hist[l0];
        int d1 = has1 ? hist[l1] : 0;
        if (d0 <= 32 && d1 <= 32) {
            int hl = lane >> 5, li = lane & 31;
            int ln = hl ? l1 : l0;
            int n = nbase + ln;
            bool valid = hl ? has1 : true;
            int deg = hl ? d1 : d0;
            int off = sc[ln];
            float sdn = valid ? sd1[n] : 0.f;
            int s = srt[off + (li < deg ? li : 0)];
            const float4 xa = *(const float4*)(xp + (size_t)s * 8);
            float x4 = xp[(size_t)s * 8 + 4];
            float t = ss1[s] + sdn;
            float e = t > 0.f ? t : NEG * t;
            if (li >= deg) e = -1e30f;
            float m = e;
#pragma unroll
            for (int o = 1; o <= 16; o <<= 1) m = fmaxf(m, __shfl_xor(m, o));
            float p = (li < deg) ? __expf(e - m) : 0.f;
            float ds = p;
#pragma unroll
            for (int o = 1; o <= 16; o <<= 1) ds += __shfl_xor(ds, o);
            float w = p * (1.0f / ds);
            float a0 = w * xa.x, a1 = w * xa.y, a2 = w * xa.z, a3 = w * xa.w, a4 = w * x4;
#pragma unroll
            for (int o = 1; o <= 16; o <<= 1) {
                a0 += __shfl_xor(a0, o); a1 += __shfl_xor(a1, o); a2 += __shfl_xor(a2, o);
                a3 += __shfl_xor(a3, o); a4 += __shfl_xor(a4, o);
            }
            float o0 = b1[li] + a0 * W1[li] + a1 * W1[64 + li] + a2 * W1[128 + li]
                     + a3 * W1[192 + li] + a4 * W1[256 + li];
            float o1 = b1[li + 32] + a0 * W1[li + 32] + a1 * W1[96 + li] + a2 * W1[160 + li]
                     + a3 * W1[224 + li] + a4 * W1[288 + li];
            o0 = fmaxf(o0, 0.f);
            o1 = fmaxf(o1, 0.f);
            float p2 = o0 * W2[li] + o1 * W2[li + 32];
#pragma unroll
            for (int o = 1; o <= 16; o <<= 1) p2 += __shfl_xor(p2, o);
            if (li == 0 && valid) h2[n] = p2;
        } else {
            agg1_gen_lds(n0g, sc[l0], d0, lane, srt, ss1, sd1, xp, W1, b1, W2, h2);
            if (has1)
                agg1_gen_lds(nbase + l1, sc[l1], d1, lane, srt, ss1, sd1, xp, W1, b1, W2, h2);
        }
    }
}

// ---------------- layer 2: full-wave single-node fallback ----------------
__device__ __forceinline__ void agg2_node(int n, int lane,
                                          const int* __restrict__ rowptr,
                                          const int* __restrict__ cntd,
                                          const int* __restrict__ adj,
                                          const float* __restrict__ h2,
                                          float as2v, float ad2v, float b2v,
                                          float* __restrict__ out) {
    int off = rowptr[n], deg = cntd[n];
    float sdn = h2[n] * ad2v;
    float m = -1e30f;
    for (int j0 = 0; j0 < deg; j0 += 64) {
        int j = j0 + lane;
        if (j < deg) {
            int s = adj[off + j];
            float e = h2[s] * as2v + sdn;
            e = e > 0.f ? e : NEG * e;
            m = fmaxf(m, e);
        }
    }
#pragma unroll
    for (int o = 32; o; o >>= 1) m = fmaxf(m, __shfl_xor(m, o));
    float dsum = 0.f, nsum = 0.f;
    for (int j0 = 0; j0 < deg; j0 += 64) {
        int j = j0 + lane;
        if (j < deg) {
            int s = adj[off + j];
            float hv = h2[s];
            float e = hv * as2v + sdn;
            e = e > 0.f ? e : NEG * e;
            float ex = __expf(e - m);
            dsum += ex;
            nsum += ex * hv;
        }
    }
#pragma unroll
    for (int o = 32; o; o >>= 1) { dsum += __shfl_xor(dsum, o); nsum += __shfl_xor(nsum, o); }
    if (lane == 0) out[n] = nsum / dsum + b2v;
}

// ---------------- layer 2: 4 nodes per wave ----------------
__global__ __launch_bounds__(256) void k_agg2(const int* __restrict__ rowptr,
                                              const int* __restrict__ cntd,
                                              const int* __restrict__ adj,
                                              const float* __restrict__ h2,
                                              const float* __restrict__ as2,
                                              const float* __restrict__ ad2,
                                              const float* __restrict__ b2,
                                              float* __restrict__ out) {
    int wid  = threadIdx.x >> 6;
    int lane = threadIdx.x & 63;
    int n0 = (blockIdx.x * 4 + wid) * 4;
    if (n0 >= NN) return;
    float as2v = as2[0], ad2v = ad2[0], b2v = b2[0];
    int d0 = cntd[n0], d1 = cntd[n0 + 1], d2 = cntd[n0 + 2], d3 = cntd[n0 + 3];

    if (d0 <= 32 && d1 <= 32 && d2 <= 32 && d3 <= 32) {
        int half = lane >> 5, li = lane & 31;
        int nA = n0 + half, nB = n0 + 2 + half;
        int offA = rowptr[nA], offB = rowptr[nB];
        int degA = half ? d1 : d0, degB = half ? d3 : d2;
        float sdA = h2[nA] * ad2v, sdB = h2[nB] * ad2v;
        float hvA = 0.f, hvB = 0.f, eA = -1e30f, eB = -1e30f;
        if (li < degA) {
            hvA = h2[adj[offA + li]];
            float t = hvA * as2v + sdA;
            eA = t > 0.f ? t : NEG * t;
        }
        if (li < degB) {
            hvB = h2[adj[offB + li]];
            float t = hvB * as2v + sdB;
            eB = t > 0.f ? t : NEG * t;
        }
        float mA = eA, mB = eB;
#pragma unroll
        for (int o = 1; o <= 16; o <<= 1) {
            mA = fmaxf(mA, __shfl_xor(mA, o));
            mB = fmaxf(mB, __shfl_xor(mB, o));
        }
        float pA = (li < degA) ? __expf(eA - mA) : 0.f;
        float pB = (li < degB) ? __expf(eB - mB) : 0.f;
        float dsA = pA, dsB = pB, nsA = pA * hvA, nsB = pB * hvB;
#pragma unroll
        for (int o = 1; o <= 16; o <<= 1) {
            dsA += __shfl_xor(dsA, o); nsA += __shfl_xor(nsA, o);
            dsB += __shfl_xor(dsB, o); nsB += __shfl_xor(nsB, o);
        }
        if (li == 0) {
            out[nA] = nsA / dsA + b2v;
            out[nB] = nsB / dsB + b2v;
        }
    } else {
        agg2_node(n0,     lane, rowptr, cntd, adj, h2, as2v, ad2v, b2v, out);
        agg2_node(n0 + 1, lane, rowptr, cntd, adj, h2, as2v, ad2v, b2v, out);
        agg2_node(n0 + 2, lane, rowptr, cntd, adj, h2, as2v, ad2v, b2v, out);
        agg2_node(n0 + 3, lane, rowptr, cntd, adj, h2, as2v, ad2v, b2v, out);
    }
}

extern "C" void kernel_launch(void* const* d_in, const int* in_sizes, int n_in,
                              void* d_out, int out_size, void* d_ws, size_t ws_size,
                              hipStream_t stream) {
    const float* x      = (const float*)d_in[0];
    const int*   ei     = (const int*)d_in[1];
    const float* W1     = (const float*)d_in[2];
    const float* a_src1 = (const float*)d_in[3];
    const float* a_dst1 = (const float*)d_in[4];
    const float* b1     = (const float*)d_in[5];
    const float* W2     = (const float*)d_in[6];
    const float* as2    = (const float*)d_in[7];
    const float* ad2    = (const float*)d_in[8];
    const float* b2     = (const float*)d_in[9];
    float* out = (float*)d_out;

    // workspace layout (all 4-byte elements)
    float* xp   = (float*)d_ws;                         // N*8 f32 = 3.2MB
    float* ss1  = xp + (size_t)NN * 8;                  // N
    float* sd1  = ss1 + NN;                             // N
    float* h2   = sd1 + NN;                             // N
    int* rowptr = (int*)(h2 + NN);                      // N
    int* cntd   = rowptr + NN;                          // N
    int* bcur   = cntd + NN;                            // 1024
    unsigned* pairs = (unsigned*)(bcur + 1024);         // NBUK*BUKCAP = 12.8MB
    int* adj    = (int*)(pairs + (size_t)NBUK * BUKCAP);// NBUK*BUKCAP = 12.8MB (no alias)

    const int NSCT = (ET + SCT_TILE - 1) / SCT_TILE;    // 416
    const int NQUAD = (NN + 15) / 16;                   // 6250 blocks, 4 nodes/wave

    k_proj<<<(NN + 3) / 4, 256, 0, stream>>>(x, W1, a_src1, a_dst1, xp, ss1, sd1, bcur);
    k_bscatter<<<NSCT, 256, 0, stream>>>(ei, bcur, pairs);
    k_fused<<<NBUK * 2, 256, 0, stream>>>(bcur, pairs, adj, rowptr, cntd,
                                          ss1, sd1, xp, W1, b1, W2, h2);
    k_agg2<<<NQUAD, 256, 0, stream>>>(rowptr, cntd, adj, h2, as2, ad2, b2, out);
}